// Round 1
// baseline (11289.600 us; speedup 1.0000x reference)
//
#include <hip/hip_runtime.h>

// ============================================================================
// Conv2Seq: conv stack -> enc ; 60-step attentive 3-layer LSTM.
// Round 0: fp32 everywhere, correctness-first.
// Key trick: keys_l are NEVER materialized. softmax(h . keys[t]) with
// keys[t] = W enc[t] + b  ==  softmax(enc[t] . (W^T h) + const), const drops.
// ============================================================================

#define BB   32
#define TT   2048
#define DIN  64
#define HH   1024
#define DOUT 64
#define NSTEP 60
#define LL1  2045
#define LL2  2038
#define LL3  2023
#define CC1  8
#define CC2  16
#define CC3  32
#define KP   8     // K-split partials for lstm gemm
#define KTILE 64   // K tile

__device__ __forceinline__ float4 ld4(const float* p){ return *(const float4*)p; }

// ---------------------------------------------------------------------------
// conv1: x[B][T][64] -> r1[B][L1][8], VALID conv over T, weights (8,64,4), ReLU
// ---------------------------------------------------------------------------
__global__ __launch_bounds__(256) void conv1_kernel(const float* __restrict__ x,
    const float* __restrict__ w, const float* __restrict__ bias,
    float* __restrict__ out){
  int idx = blockIdx.x*256 + threadIdx.x;
  if (idx >= BB*LL1) return;
  int b = idx / LL1, t = idx % LL1;
  float acc[CC1];
  #pragma unroll
  for (int c=0;c<CC1;++c) acc[c] = bias[c];
  for (int k=0;k<4;++k){
    const float* xr = x + ((size_t)(b*TT + t + k))*DIN;
    for (int d=0; d<DIN; d+=4){
      float4 v = ld4(xr + d);
      #pragma unroll
      for (int c=0;c<CC1;++c){   // w[c][d][k] uniform across lanes -> s_load
        acc[c] += v.x * w[((c*DIN+d  )<<2)+k]
                + v.y * w[((c*DIN+d+1)<<2)+k]
                + v.z * w[((c*DIN+d+2)<<2)+k]
                + v.w * w[((c*DIN+d+3)<<2)+k];
      }
    }
  }
  float* o = out + (size_t)idx*CC1;
  #pragma unroll
  for (int c=0;c<CC1;++c) o[c] = fmaxf(acc[c], 0.f);
}

// ---------------------------------------------------------------------------
// conv2: r1[B][L1][8] -> r2[B][L2][16], weights (16,8,8), ReLU
// ---------------------------------------------------------------------------
__global__ __launch_bounds__(256) void conv2_kernel(const float* __restrict__ r1,
    const float* __restrict__ w, const float* __restrict__ bias,
    float* __restrict__ out){
  int idx = blockIdx.x*256 + threadIdx.x;
  if (idx >= BB*LL2) return;
  int b = idx / LL2, t = idx % LL2;
  float acc[CC2];
  #pragma unroll
  for (int c=0;c<CC2;++c) acc[c] = bias[c];
  for (int k=0;k<8;++k){
    const float* rr = r1 + ((size_t)(b*LL1 + t + k))*CC1;
    for (int c1=0;c1<CC1;c1+=4){
      float4 v = ld4(rr + c1);
      #pragma unroll
      for (int c=0;c<CC2;++c){   // w[c][c1][k]
        acc[c] += v.x * w[((c*CC1+c1  )<<3)+k]
                + v.y * w[((c*CC1+c1+1)<<3)+k]
                + v.z * w[((c*CC1+c1+2)<<3)+k]
                + v.w * w[((c*CC1+c1+3)<<3)+k];
      }
    }
  }
  float* o = out + (size_t)idx*CC2;
  #pragma unroll
  for (int c=0;c<CC2;++c) o[c] = fmaxf(acc[c], 0.f);
}

// ---------------------------------------------------------------------------
// conv3: r2[B][L2][16] -> enc[B][L3][32], weights (32,16,16), ReLU
// ---------------------------------------------------------------------------
__global__ __launch_bounds__(256) void conv3_kernel(const float* __restrict__ r2,
    const float* __restrict__ w, const float* __restrict__ bias,
    float* __restrict__ out){
  int idx = blockIdx.x*256 + threadIdx.x;
  if (idx >= BB*LL3) return;
  int b = idx / LL3, t = idx % LL3;
  float acc[CC3];
  #pragma unroll
  for (int c=0;c<CC3;++c) acc[c] = bias[c];
  for (int k=0;k<16;++k){
    const float* rr = r2 + ((size_t)(b*LL2 + t + k))*CC2;
    for (int c2=0;c2<CC2;c2+=4){
      float4 v = ld4(rr + c2);
      #pragma unroll
      for (int c=0;c<CC3;++c){   // w[c][c2][k]
        acc[c] += v.x * w[((c*CC2+c2  )<<4)+k]
                + v.y * w[((c*CC2+c2+1)<<4)+k]
                + v.z * w[((c*CC2+c2+2)<<4)+k]
                + v.w * w[((c*CC2+c2+3)<<4)+k];
      }
    }
  }
  float* o = out + (size_t)idx*CC3;
  #pragma unroll
  for (int c=0;c<CC3;++c) o[c] = fmaxf(acc[c], 0.f);
}

// ---------------------------------------------------------------------------
// init: h[l][parity0]=0, c=0, prev[0]=x[:,T-1,:]
// h layout: [3][2][B][H]; c: [3][B][H]; prev: [2][B][64]
// ---------------------------------------------------------------------------
__global__ __launch_bounds__(256) void init_kernel(const float* __restrict__ x,
    float* __restrict__ hbuf, float* __restrict__ cbuf, float* __restrict__ prev){
  int idx = blockIdx.x*256 + threadIdx.x;
  if (idx < 3*BB*HH){
    int l = idx/(BB*HH); int r = idx%(BB*HH);
    hbuf[(l*2+0)*BB*HH + r] = 0.f;
    cbuf[idx] = 0.f;
  }
  if (idx < BB*DIN){
    int b = idx/DIN, d = idx%DIN;
    prev[idx] = x[((size_t)b*TT + (TT-1))*DIN + d];
  }
}

// ---------------------------------------------------------------------------
// attend: for (l,b): q = w_a^T h ; scores[t] = enc[b,t,:].q ; softmax over t ;
//         ctx = sum_t p[t] enc[b,t,:].  grid = 96 blocks (3 layers x 32 b).
// ---------------------------------------------------------------------------
__global__ __launch_bounds__(256) void attend_kernel(
    const float* __restrict__ enc, const float* __restrict__ hbuf,
    const float* __restrict__ wa1, const float* __restrict__ wa2,
    const float* __restrict__ wa3, float* __restrict__ ctx, int p){
  int l = blockIdx.x >> 5, b = blockIdx.x & 31;
  const float* wa = (l==0) ? wa1 : ((l==1) ? wa2 : wa3);
  const float* h  = hbuf + (size_t)((l*2 + p)*BB + b)*HH;

  __shared__ float sh[HH];
  __shared__ float sq[32];
  __shared__ float ss[LL3+1];
  __shared__ float red[256];

  int tid = threadIdx.x;
  { float4 v = ld4(h + tid*4); *(float4*)&sh[tid*4] = v; }
  __syncthreads();

  // q[c] = sum_k wa[k][c] * h[k]   (wa is (H,32))
  int cc = tid & 31, g = tid >> 5;
  float part = 0.f;
  for (int kk = g; kk < HH; kk += 8) part += wa[kk*32 + cc] * sh[kk];
  red[tid] = part; __syncthreads();
  if (tid < 32){ float s = 0.f;
    #pragma unroll
    for (int gg=0; gg<8; ++gg) s += red[gg*32 + tid];
    sq[tid] = s; }
  __syncthreads();

  // scores + max
  const float* eb = enc + (size_t)b*LL3*CC3;
  float lmax = -1e30f;
  for (int t = tid; t < LL3; t += 256){
    const float* er = eb + t*32;
    float dot = 0.f;
    #pragma unroll
    for (int c=0;c<32;c+=4){ float4 v = ld4(er+c);
      dot += v.x*sq[c] + v.y*sq[c+1] + v.z*sq[c+2] + v.w*sq[c+3]; }
    ss[t] = dot; lmax = fmaxf(lmax, dot);
  }
  red[tid] = lmax; __syncthreads();
  for (int s=128; s>0; s>>=1){ if (tid<s) red[tid] = fmaxf(red[tid], red[tid+s]); __syncthreads(); }
  float m = red[0]; __syncthreads();

  // exp + sum
  float lsum = 0.f;
  for (int t = tid; t < LL3; t += 256){ float e = __expf(ss[t]-m); ss[t] = e; lsum += e; }
  red[tid] = lsum; __syncthreads();
  for (int s=128; s>0; s>>=1){ if (tid<s) red[tid] += red[tid+s]; __syncthreads(); }
  float rZ = 1.0f / red[0]; __syncthreads();

  // ctx[c] = (sum_t p[t]*enc[t][c]) / Z
  float acc = 0.f;
  for (int t = g; t < LL3; t += 8) acc += ss[t] * eb[t*32 + cc];
  red[tid] = acc; __syncthreads();
  if (tid < 32){ float s = 0.f;
    #pragma unroll
    for (int gg=0; gg<8; ++gg) s += red[gg*32 + tid];
    ctx[(l*BB + b)*32 + tid] = s * rZ; }
}

// ---------------------------------------------------------------------------
// lstm_gemm: partial[kp][b][row] = sum_{k in kp-stripe} in[b][k] * W[row][k]
//   in = concat(ctx(32), z(Kz), hold(1024));  W = concat(wih, whh) along k.
// grid = 256 blocks: rc = blk&31 (128 rows each), kp = blk>>5 (K-split of 8).
// 256 thr, thread tile 4b x 4rows (interleaved by 8/32 -> conflict-free LDS).
// ---------------------------------------------------------------------------
__global__ __launch_bounds__(256) void lstm_gemm(
    const float* __restrict__ ctxv, const float* __restrict__ z,
    const float* __restrict__ hold, const float* __restrict__ wih,
    const float* __restrict__ whh,  float* __restrict__ partial, int Kz){
  const int Kih = 32 + Kz;
  const int Kin = Kih + HH;
  const int tid = threadIdx.x;
  const int rc  = blockIdx.x & 31;
  const int kp  = blockIdx.x >> 5;

  __shared__ float lin[32][KTILE+4];
  __shared__ float lw[128][KTILE+4];

  float acc[4][4];
  #pragma unroll
  for (int i=0;i<4;++i)
    #pragma unroll
    for (int j=0;j<4;++j) acc[i][j] = 0.f;

  const int nTiles = (Kin + KTILE - 1) / KTILE;
  const int bg = tid & 7;
  const int rg = tid >> 3;

  for (int tile = kp; tile < nTiles; tile += KP){
    const int k0 = tile * KTILE;
    // stage input rows: 32 x 64 floats
    #pragma unroll
    for (int i=0;i<2;++i){
      int slot = tid + 256*i;
      int bb = slot >> 4, kc = slot & 15;
      int k = k0 + kc*4;
      float4 v = make_float4(0.f,0.f,0.f,0.f);
      if (k < 32)       v = ld4(ctxv + bb*32 + k);
      else if (k < Kih) v = ld4(z + (size_t)bb*Kz + (k-32));
      else if (k < Kin) v = ld4(hold + (size_t)bb*HH + (k-Kih));
      *(float4*)&lin[bb][kc*4] = v;
    }
    // stage weight rows: 128 x 64 floats
    #pragma unroll
    for (int i=0;i<8;++i){
      int slot = tid + 256*i;
      int rloc = slot >> 4, kc = slot & 15;
      int k = k0 + kc*4;
      int grow = rc*128 + rloc;
      float4 v = make_float4(0.f,0.f,0.f,0.f);
      if (k < Kih)      v = ld4(wih + (size_t)grow*Kih + k);
      else if (k < Kin) v = ld4(whh + (size_t)grow*HH + (k-Kih));
      *(float4*)&lw[rloc][kc*4] = v;
    }
    __syncthreads();
    #pragma unroll
    for (int kk=0; kk<KTILE/4; ++kk){
      float4 a[4], w4[4];
      #pragma unroll
      for (int i=0;i<4;++i) a[i]  = *(const float4*)&lin[bg + 8*i][kk*4];
      #pragma unroll
      for (int j=0;j<4;++j) w4[j] = *(const float4*)&lw[rg + 32*j][kk*4];
      #pragma unroll
      for (int i=0;i<4;++i)
        #pragma unroll
        for (int j=0;j<4;++j)
          acc[i][j] += a[i].x*w4[j].x + a[i].y*w4[j].y
                     + a[i].z*w4[j].z + a[i].w*w4[j].w;
    }
    __syncthreads();
  }
  #pragma unroll
  for (int i=0;i<4;++i){
    int b = bg + 8*i;
    #pragma unroll
    for (int j=0;j<4;++j){
      int grow = rc*128 + rg + 32*j;
      partial[((size_t)(kp*BB + b) << 12) + grow] = acc[i][j];
    }
  }
}

// ---------------------------------------------------------------------------
// cell: gates = sum partials + bih + bhh ; LSTM cell ; c in-place, h -> h[l][pn]
// ---------------------------------------------------------------------------
__global__ __launch_bounds__(256) void cell_kernel(
    const float* __restrict__ part, const float* __restrict__ bih,
    const float* __restrict__ bhh, float* __restrict__ cbuf,
    float* __restrict__ hnew){
  int idx = blockIdx.x*256 + threadIdx.x;   // 32768
  int b = idx >> 10, jj = idx & 1023;
  float g[4];
  #pragma unroll
  for (int q=0;q<4;++q){
    int row = q*1024 + jj;
    float s = bih[row] + bhh[row];
    #pragma unroll
    for (int p=0;p<KP;++p) s += part[((size_t)(p*BB + b) << 12) + row];
    g[q] = s;
  }
  float gi = 1.f/(1.f + __expf(-g[0]));
  float gf = 1.f/(1.f + __expf(-g[1]));
  float gg = tanhf(g[2]);
  float go = 1.f/(1.f + __expf(-g[3]));
  float cn = gf*cbuf[idx] + gi*gg;
  cbuf[idx] = cn;
  hnew[idx] = go * tanhf(cn);
}

// ---------------------------------------------------------------------------
// out: y = h3 @ w_out^T + b_out -> d_out[b][s][:] and prev[pn]
// ---------------------------------------------------------------------------
__global__ __launch_bounds__(64) void out_kernel(
    const float* __restrict__ h3, const float* __restrict__ wout,
    const float* __restrict__ bout, float* __restrict__ dout,
    float* __restrict__ prevn, int s){
  int b = blockIdx.x, d = threadIdx.x;
  __shared__ float sh[HH];
  for (int i = threadIdx.x; i < HH/4; i += 64)
    *(float4*)&sh[i*4] = ld4(h3 + (size_t)b*HH + i*4);
  __syncthreads();
  const float* wr = wout + (size_t)d*HH;
  float acc = bout[d];
  for (int k=0;k<HH;k+=4){ float4 w4 = ld4(wr+k);
    acc += w4.x*sh[k] + w4.y*sh[k+1] + w4.z*sh[k+2] + w4.w*sh[k+3]; }
  dout[((size_t)b*NSTEP + s)*DOUT + d] = acc;
  prevn[b*DOUT + d] = acc;
}

// ---------------------------------------------------------------------------
extern "C" void kernel_launch(void* const* d_in, const int* in_sizes, int n_in,
                              void* d_out, int out_size, void* d_ws, size_t ws_size,
                              hipStream_t stream) {
  const float* x    = (const float*)d_in[0];
  const float* w_c1 = (const float*)d_in[1];
  const float* b_c1 = (const float*)d_in[2];
  const float* w_c2 = (const float*)d_in[3];
  const float* b_c2 = (const float*)d_in[4];
  const float* w_c3 = (const float*)d_in[5];
  const float* b_c3 = (const float*)d_in[6];
  const float* w_a1 = (const float*)d_in[7];
  const float* w_a2 = (const float*)d_in[9];
  const float* w_a3 = (const float*)d_in[11];
  const float* wih1 = (const float*)d_in[13];
  const float* whh1 = (const float*)d_in[14];
  const float* bih1 = (const float*)d_in[15];
  const float* bhh1 = (const float*)d_in[16];
  const float* wih2 = (const float*)d_in[17];
  const float* whh2 = (const float*)d_in[18];
  const float* bih2 = (const float*)d_in[19];
  const float* bhh2 = (const float*)d_in[20];
  const float* wih3 = (const float*)d_in[21];
  const float* whh3 = (const float*)d_in[22];
  const float* bih3 = (const float*)d_in[23];
  const float* bhh3 = (const float*)d_in[24];
  const float* wout = (const float*)d_in[25];
  const float* bout = (const float*)d_in[26];

  float* ws = (float*)d_ws;
  size_t off = 0;
  float* enc  = ws + off; off += (size_t)BB*LL3*CC3;      // 2,071,552
  float* r1   = ws + off; off += (size_t)BB*LL1*CC1;      //   523,520
  float* r2   = ws + off; off += (size_t)BB*LL2*CC2;      // 1,043,456
  float* hbuf = ws + off; off += (size_t)3*2*BB*HH;       //   196,608
  float* cbuf = ws + off; off += (size_t)3*BB*HH;         //    98,304
  float* prev = ws + off; off += (size_t)2*BB*DIN;        //     4,096
  float* ctx  = ws + off; off += (size_t)3*BB*32;         //     3,072
  float* part = ws + off; off += (size_t)KP*BB*4096;      // 1,048,576

  conv1_kernel<<<(BB*LL1+255)/256, 256, 0, stream>>>(x, w_c1, b_c1, r1);
  conv2_kernel<<<(BB*LL2+255)/256, 256, 0, stream>>>(r1, w_c2, b_c2, r2);
  conv3_kernel<<<(BB*LL3+255)/256, 256, 0, stream>>>(r2, w_c3, b_c3, enc);
  init_kernel<<<(3*BB*HH+255)/256, 256, 0, stream>>>(x, hbuf, cbuf, prev);

  for (int s = 0; s < NSTEP; ++s){
    int p = s & 1, pn = p ^ 1;
    attend_kernel<<<96, 256, 0, stream>>>(enc, hbuf, w_a1, w_a2, w_a3, ctx, p);

    // layer 1: in = [ctx1, prev(64), h1_old]
    lstm_gemm<<<256, 256, 0, stream>>>(ctx + 0*BB*32, prev + p*BB*DIN,
        hbuf + (size_t)(0*2+p)*BB*HH, wih1, whh1, part, DIN);
    cell_kernel<<<128, 256, 0, stream>>>(part, bih1, bhh1,
        cbuf + 0*BB*HH, hbuf + (size_t)(0*2+pn)*BB*HH);

    // layer 2: in = [ctx2, h1_new(1024), h2_old]
    lstm_gemm<<<256, 256, 0, stream>>>(ctx + 1*BB*32, hbuf + (size_t)(0*2+pn)*BB*HH,
        hbuf + (size_t)(1*2+p)*BB*HH, wih2, whh2, part, HH);
    cell_kernel<<<128, 256, 0, stream>>>(part, bih2, bhh2,
        cbuf + 1*BB*HH, hbuf + (size_t)(1*2+pn)*BB*HH);

    // layer 3: in = [ctx3, h2_new(1024), h3_old]
    lstm_gemm<<<256, 256, 0, stream>>>(ctx + 2*BB*32, hbuf + (size_t)(1*2+pn)*BB*HH,
        hbuf + (size_t)(2*2+p)*BB*HH, wih3, whh3, part, HH);
    cell_kernel<<<128, 256, 0, stream>>>(part, bih3, bhh3,
        cbuf + 2*BB*HH, hbuf + (size_t)(2*2+pn)*BB*HH);

    out_kernel<<<32, 64, 0, stream>>>(hbuf + (size_t)(2*2+pn)*BB*HH, wout, bout,
        (float*)d_out, prev + pn*BB*DIN, s);
  }
}